// Round 14
// baseline (251.183 us; speedup 1.0000x reference)
//
#include <hip/hip_runtime.h>
#include <stdint.h>

#define IMPOSSIBLE -10000.0f
#define TT 4096
#define NN 64
#define BB 64
#define CHUNK 64            // quad: each wave runs chunks q, q+16, q+32, q+48
#define WARM 16             // R12-validated (0.34^15 ~ 1e-7 nats/boundary)
#define NI (WARM + CHUNK - 1)  // 79 unified iterations per wave

typedef _Float16 half2_t __attribute__((ext_vector_type(2)));

__device__ __forceinline__ float fdot2f(half2_t a, half2_t b, float c) {
#if __has_builtin(__builtin_amdgcn_fdot2)
  return __builtin_amdgcn_fdot2(a, b, c, false);
#else
  return c + (float)a[0] * (float)b[0] + (float)a[1] * (float)b[1];
#endif
}

// ---- bool-input dtype shim: harness may pass jnp.bool as int32 or uint8 ----
__device__ __forceinline__ bool bools_are_i32(const void* mask) {
  return ((const unsigned int*)mask)[0] == 1u;
}
__device__ __forceinline__ int bget(const void* p, int idx, bool i32) {
  return i32 ? ((const int*)p)[idx] : (int)((const unsigned char*)p)[idx];
}

// ---- DPP wave-64 reductions (VALU only) ----
__device__ __forceinline__ float wave_max_f32(float x) {
  int t;
#define STEP(ctrl)                                                            \
  t = __builtin_amdgcn_update_dpp(__float_as_int(x), __float_as_int(x), ctrl, \
                                  0xf, 0xf, false);                           \
  x = fmaxf(x, __int_as_float(t));
  STEP(0x111) STEP(0x112) STEP(0x114) STEP(0x118) STEP(0x142) STEP(0x143)
#undef STEP
  return __int_as_float(__builtin_amdgcn_readlane(__float_as_int(x), 63));
}

__device__ __forceinline__ float wave_sum_f32(float x) {
  int t;
#define STEP(ctrl)                                                         \
  t = __builtin_amdgcn_update_dpp(0, __float_as_int(x), ctrl, 0xf, 0xf,    \
                                  true);                                   \
  x += __int_as_float(t);
  STEP(0x111) STEP(0x112) STEP(0x114) STEP(0x118) STEP(0x142) STEP(0x143)
#undef STEP
  return __int_as_float(__builtin_amdgcn_readlane(__float_as_int(x), 63));
}

__device__ __forceinline__ int wave_sum_i32(int x) {
  int t;
#define STEP(ctrl)                                                      \
  t = __builtin_amdgcn_update_dpp(0, x, ctrl, 0xf, 0xf, true);          \
  x += t;
  STEP(0x111) STEP(0x112) STEP(0x114) STEP(0x118) STEP(0x142) STEP(0x143)
#undef STEP
  return __builtin_amdgcn_readlane(x, 63);
}

__device__ __forceinline__ float wave_lse(float x) {
  float m = wave_max_f32(x);
  float s = wave_sum_f32(__expf(x - m));
  return m + __logf(s);
}

__device__ __forceinline__ int bytesum4(unsigned int u) {
  return (int)((u * 0x01010101u) >> 24);  // bytes are 0/1, sum <= 4
}

// ---------------- z1: FOUR chains per wave at 1 wave/SIMD -------------------
// Measured trajectory: per-chain-step cost 672cy (1 chain, 2w/SIMD, R12),
// 650cy (2 chains, 2w/SIMD, R13, VALUBusy 59%), 905cy (2 chains, 1w/SIMD,
// R9). The cost floor is the VALU ISSUE time of the step (~320-380cy of
// instructions); overlap only strips latency. VALUBusy at 59% leaves exactly
// one doubling: 4 chains/wave, CHUNK=64, 1024 waves (1/SIMD), 79 iters/wave,
// 4 chain-steps per iteration. Pairwise read/fdot scheduling (A,B then C,D)
// caps live qa registers at 64 and hides pair-2's DS latency under pair-1's
// fdot tree. launch_bounds(64,1): VGPR cap 512, no spill (watch WRITE_SIZE).
// Body = R13 (harness-verified, absmax 0.0) extended symmetrically.
__global__ __launch_bounds__(64, 1) void crf_z1(
    const float* __restrict__ em, const void* __restrict__ mask,
    const float* __restrict__ trans, const float* __restrict__ startv,
    const float* __restrict__ endv, const void* __restrict__ ftr,
    const void* __restrict__ fst, const void* __restrict__ fen,
    float* __restrict__ out) {
  const int lane = threadIdx.x;
  const int b = blockIdx.x >> 4;   // 16 chunk-quads per batch
  const int q = blockIdx.x & 15;
  const bool i32 = bools_are_i32(mask);

  // len[b] = sum(mask[b, :])
  int ls = 0;
  if (i32) {
    const uint4* mv = (const uint4*)((const int*)mask + (size_t)b * TT);
#pragma unroll
    for (int k = 0; k < 16; ++k) {               // 1024 uint4 = 4096 ints
      uint4 w = mv[k * 64 + lane];
      ls += (int)(w.x + w.y + w.z + w.w);
    }
  } else {
    const uint4* mv = (const uint4*)((const unsigned char*)mask + (size_t)b * TT);
#pragma unroll
    for (int k = 0; k < 4; ++k) {                // 256 uint4 = 4096 bytes
      uint4 w = mv[k * 64 + lane];
      ls += bytesum4(w.x) + bytesum4(w.y) + bytesum4(w.z) + bytesum4(w.w);
    }
  }
  const int len = wave_sum_i32(ls);

  // chains j=0..3 handle chunks q+16j. j=0,1 (chunks 0..31): always fully
  // in-sequence (L+CHUNK <= 2048 <= len). j=2,3 may be partial/inactive.
  int L[4], tlo[4], thi[4];
  bool act[4];
#pragma unroll
  for (int j = 0; j < 4; ++j) {
    L[j] = (q + 16 * j) * CHUNK;
    act[j] = (L[j] < len);
    thi[j] = min(L[j] + CHUNK - 1, len - 1);  // < tlo when inactive
  }

  // ET[i][j] = exp(masked trans[i][j]); lane j holds column j as 32 f16 pairs
  half2_t et2[32];
#pragma unroll
  for (int i2 = 0; i2 < 32; ++i2) {
    int i0 = 2 * i2, i1 = 2 * i2 + 1;
    float t0 = trans[i0 * NN + lane];
    float t1 = trans[i1 * NN + lane];
    if (bget(ftr, i0 * NN + lane, i32)) t0 = IMPOSSIBLE;
    if (bget(ftr, i1 * NN + lane, i32)) t1 = IMPOSSIBLE;
    half2_t h;
    h[0] = (_Float16)__expf(t0);
    h[1] = (_Float16)__expf(t1);
    et2[i2] = h;
  }

  const float* emb = em + (size_t)b * TT * NN + lane;

  float n[4], S[4];
#pragma unroll
  for (int j = 0; j < 4; ++j) S[j] = 0.f;

  if (q == 0) {  // chain 0 is chunk 0: true start
    float sv = startv[lane];
    if (bget(fst, lane, i32)) sv = IMPOSSIBLE;
    n[0] = sv + emb[0];
    tlo[0] = 1;
  } else {
    n[0] = emb[(size_t)(L[0] - WARM) * NN];
    tlo[0] = L[0] - WARM + 1;
  }
#pragma unroll
  for (int j = 1; j < 4; ++j) {
    n[j] = emb[(size_t)(L[j] - WARM) * NN];  // safe: L >= 1024, <= 4032
    tlo[j] = L[j] - WARM + 1;
  }

  __shared__ __align__(16) _Float16 pbuf[4][2][64];  // [chain][parity][64]

  // depth-4 em prefetch rings (one per chain); no barrier, no waitcnt asm.
  float r[4][4];
#pragma unroll
  for (int j = 0; j < 4; ++j)
#pragma unroll
    for (int k = 0; k < 4; ++k)
      r[j][k] = emb[(size_t)min(tlo[j] + k, TT - 1) * NN];

  for (int i = 0; i < NI; ++i) {
    float rn[4], mm[4], pp[4];
#pragma unroll
    for (int j = 0; j < 4; ++j)
      rn[j] = emb[(size_t)min(tlo[j] + i + 4, TT - 1) * NN];  // prefetch
#pragma unroll
    for (int j = 0; j < 4; ++j) mm[j] = wave_max_f32(n[j]);
#pragma unroll
    for (int j = 0; j < 4; ++j) pp[j] = __expf(n[j] - mm[j]);
    const int par = i & 1;
#pragma unroll
    for (int j = 0; j < 4; ++j) pbuf[j][par][lane] = (_Float16)pp[j];
    // same-wave DS in-order (R10-verified): no explicit waitcnt.
    __builtin_amdgcn_sched_barrier(0);

    float s[4];
    // ---- pair 1: chains 0,1 ----
    {
      const uint4* pv0 = (const uint4*)pbuf[0][par];
      const uint4* pv1 = (const uint4*)pbuf[1][par];
      uint4 qa[8], qb[8];
#pragma unroll
      for (int k = 0; k < 8; ++k) qa[k] = pv0[k];
#pragma unroll
      for (int k = 0; k < 8; ++k) qb[k] = pv1[k];
      __builtin_amdgcn_sched_barrier(0);
      float a0 = 0.f, a1 = 0.f, a2 = 0.f, a3 = 0.f;
      float b0 = 0.f, b1 = 0.f, b2 = 0.f, b3 = 0.f;
#pragma unroll
      for (int k = 0; k < 8; ++k) {
        a0 = fdot2f(__builtin_bit_cast(half2_t, qa[k].x), et2[4 * k + 0], a0);
        a1 = fdot2f(__builtin_bit_cast(half2_t, qa[k].y), et2[4 * k + 1], a1);
        a2 = fdot2f(__builtin_bit_cast(half2_t, qa[k].z), et2[4 * k + 2], a2);
        a3 = fdot2f(__builtin_bit_cast(half2_t, qa[k].w), et2[4 * k + 3], a3);
        b0 = fdot2f(__builtin_bit_cast(half2_t, qb[k].x), et2[4 * k + 0], b0);
        b1 = fdot2f(__builtin_bit_cast(half2_t, qb[k].y), et2[4 * k + 1], b1);
        b2 = fdot2f(__builtin_bit_cast(half2_t, qb[k].z), et2[4 * k + 2], b2);
        b3 = fdot2f(__builtin_bit_cast(half2_t, qb[k].w), et2[4 * k + 3], b3);
      }
      s[0] = (a0 + a1) + (a2 + a3);
      s[1] = (b0 + b1) + (b2 + b3);
    }
    // ---- pair 2: chains 2,3 (reads overlap pair-1 tail via DS pipe) ----
    {
      const uint4* pv2 = (const uint4*)pbuf[2][par];
      const uint4* pv3 = (const uint4*)pbuf[3][par];
      uint4 qa[8], qb[8];
#pragma unroll
      for (int k = 0; k < 8; ++k) qa[k] = pv2[k];
#pragma unroll
      for (int k = 0; k < 8; ++k) qb[k] = pv3[k];
      __builtin_amdgcn_sched_barrier(0);
      float a0 = 0.f, a1 = 0.f, a2 = 0.f, a3 = 0.f;
      float b0 = 0.f, b1 = 0.f, b2 = 0.f, b3 = 0.f;
#pragma unroll
      for (int k = 0; k < 8; ++k) {
        a0 = fdot2f(__builtin_bit_cast(half2_t, qa[k].x), et2[4 * k + 0], a0);
        a1 = fdot2f(__builtin_bit_cast(half2_t, qa[k].y), et2[4 * k + 1], a1);
        a2 = fdot2f(__builtin_bit_cast(half2_t, qa[k].z), et2[4 * k + 2], a2);
        a3 = fdot2f(__builtin_bit_cast(half2_t, qa[k].w), et2[4 * k + 3], a3);
        b0 = fdot2f(__builtin_bit_cast(half2_t, qb[k].x), et2[4 * k + 0], b0);
        b1 = fdot2f(__builtin_bit_cast(half2_t, qb[k].y), et2[4 * k + 1], b1);
        b2 = fdot2f(__builtin_bit_cast(half2_t, qb[k].z), et2[4 * k + 2], b2);
        b3 = fdot2f(__builtin_bit_cast(half2_t, qb[k].w), et2[4 * k + 3], b3);
      }
      s[2] = (a0 + a1) + (a2 + a3);
      s[3] = (b0 + b1) + (b2 + b3);
    }

    // act-gated updates (wave-uniform -> cndmask, no divergence)
#pragma unroll
    for (int j = 0; j < 4; ++j) {
      const bool a_ = (tlo[j] + i <= thi[j]);
      n[j] = a_ ? (__logf(s[j]) + r[j][0]) : n[j];
      S[j] += a_ ? mm[j] : 0.f;
      r[j][0] = r[j][1]; r[j][1] = r[j][2]; r[j][2] = r[j][3]; r[j][3] = rn[j];
    }
    if (i == WARM - 2) {  // t == cL-1: discard warm-up scale
      if (q > 0) S[0] = -wave_lse(n[0]);      // chain 0 warm unless chunk 0
      S[1] = -wave_lse(n[1]);                 // chains 1: always warm-started
      if (act[2]) S[2] = -wave_lse(n[2]);
      if (act[3]) S[3] = -wave_lse(n[3]);
    }
  }

  float ev = endv[lane];
  if (bget(fen, lane, i32)) ev = IMPOSSIBLE;
  float res = 0.f;
#pragma unroll
  for (int j = 0; j < 4; ++j) {
    if (act[j]) {
      const bool hasEnd = (len <= L[j] + CHUNK);
      float zc = hasEnd ? wave_lse(n[j] + ev) : wave_lse(n[j]);
      res += S[j] + zc;
    }
  }
  if (lane == 0) atomicAdd(out + b, res);
}

// ---------------- z0: gold-path score, wave-per-row ballot version ----------
// (unchanged: ~12 us under the overhead model)
__global__ __launch_bounds__(256) void crf_z0(
    const float* __restrict__ em, const void* __restrict__ mask,
    const void* __restrict__ target, const float* __restrict__ trans,
    const float* __restrict__ startv, const float* __restrict__ endv,
    const void* __restrict__ ftr, const void* __restrict__ fst,
    const void* __restrict__ fen, float* __restrict__ out) {
  const int tid = threadIdx.x;
  const int lane = tid & 63;
  const int w = tid >> 6;
  const int b = blockIdx.x >> 4;
  const int q = blockIdx.x & 15;
  const bool i32 = bools_are_i32(mask);

  __shared__ int lred[4];
  __shared__ int tags[257];
  __shared__ float fred4[4];

  // ---- block-wide len[b] = sum(mask[b,:]) ----
  int ls = 0;
  if (i32) {
    const uint4* mv = (const uint4*)((const int*)mask + (size_t)b * TT);
#pragma unroll
    for (int k = 0; k < 4; ++k) {   // 1024 uint4 = 4096 ints
      uint4 u = mv[k * 256 + tid];
      ls += (int)(u.x + u.y + u.z + u.w);
    }
  } else {
    uint4 u = ((const uint4*)((const unsigned char*)mask + (size_t)b * TT))[tid];
    ls = bytesum4(u.x) + bytesum4(u.y) + bytesum4(u.z) + bytesum4(u.w);
  }
  ls = wave_sum_i32(ls);
  if (lane == 0) lred[w] = ls;

  // ---- tag extraction: wave w scans rows t0 + w*64 .. +63 ----
  const int t0 = q * 256;
  int mytag = 0;
  const size_t rb = ((size_t)b * TT + t0 + (size_t)w * 64) * NN + lane;
  if (i32) {
    const int* tg = (const int*)target + rb;
    for (int k = 0; k < 8; ++k) {
      int v[8];
#pragma unroll
      for (int j = 0; j < 8; ++j) v[j] = tg[(size_t)(k * 8 + j) * NN];
#pragma unroll
      for (int j = 0; j < 8; ++j) {
        unsigned long long bm = __ballot(v[j] != 0);
        int tv = __ffsll(bm) - 1;
        if (lane == k * 8 + j) mytag = tv;
      }
    }
  } else {
    const unsigned char* tg = (const unsigned char*)target + rb;
    for (int k = 0; k < 8; ++k) {
      int v[8];
#pragma unroll
      for (int j = 0; j < 8; ++j) v[j] = (int)tg[(size_t)(k * 8 + j) * NN];
#pragma unroll
      for (int j = 0; j < 8; ++j) {
        unsigned long long bm = __ballot(v[j] != 0);
        int tv = __ffsll(bm) - 1;
        if (lane == k * 8 + j) mytag = tv;
      }
    }
  }
  tags[tid + 1] = mytag;
  if (w == 0) {  // boundary row t0-1 for the block's first transition
    int rp = (t0 == 0) ? 0 : t0 - 1;
    int vv = i32 ? ((const int*)target)[((size_t)b * TT + rp) * NN + lane]
                 : (int)((const unsigned char*)
                       target)[((size_t)b * TT + rp) * NN + lane];
    unsigned long long bm = __ballot(vv != 0);
    int tv = __ffsll(bm) - 1;
    if (tid == 0) tags[0] = (t0 == 0) ? 0 : tv;
  }
  __syncthreads();  // publish lred + tags
  const int len = lred[0] + lred[1] + lred[2] + lred[3];

  const int t = t0 + tid;
  float contrib = 0.f;
  if (t < len) {
    int tg = tags[tid + 1];
    float emv = em[((size_t)b * TT + t) * NN + tg];
    if (t == 0) {
      float sv = startv[tg];
      if (bget(fst, tg, i32)) sv = IMPOSSIBLE;
      contrib = sv + emv;
    } else {
      int tp = tags[tid];
      float tv = trans[tp * NN + tg];
      if (bget(ftr, tp * NN + tg, i32)) tv = IMPOSSIBLE;
      contrib = tv + emv;
    }
    if (t == len - 1) {
      float evv = endv[tg];
      if (bget(fen, tg, i32)) evv = IMPOSSIBLE;
      contrib += evv;
    }
  }
  float wsum = wave_sum_f32(contrib);
  if (lane == 0) fred4[w] = wsum;
  __syncthreads();
  if (tid == 0)
    atomicAdd(out + b, -(fred4[0] + fred4[1] + fred4[2] + fred4[3]));
}

extern "C" void kernel_launch(void* const* d_in, const int* in_sizes, int n_in,
                              void* d_out, int out_size, void* d_ws,
                              size_t ws_size, hipStream_t stream) {
  const float* em = (const float*)d_in[0];
  const void* mask = d_in[1];
  const void* target = d_in[2];
  const float* trans = (const float*)d_in[3];
  const float* startv = (const float*)d_in[4];
  const float* endv = (const float*)d_in[5];
  const void* ftr = d_in[6];
  const void* fst = d_in[7];
  const void* fen = d_in[8];
  float* out = (float*)d_out;

  hipMemsetAsync(out, 0, BB * sizeof(float), stream);
  crf_z1<<<dim3(BB * 16), dim3(64), 0, stream>>>(em, mask, trans, startv,
                                                 endv, ftr, fst, fen, out);
  crf_z0<<<dim3(BB * 16), dim3(256), 0, stream>>>(
      em, mask, target, trans, startv, endv, ftr, fst, fen, out);
}

// Round 15
// 188.310 us; speedup vs baseline: 1.3339x; 1.3339x over previous
//
#include <hip/hip_runtime.h>
#include <stdint.h>

#define IMPOSSIBLE -10000.0f
#define TT 4096
#define NN 64
#define BB 64
#define CHUNK 32            // 128 chunks/batch, 16 chains per wave, 8 waves/batch
#define WARM 20             // 0.34^19 ~ 1e-9/boundary x127 -> 1e-7 nats total
#define NI (WARM + CHUNK - 1)  // 51 iterations per wave
#define WPB 8               // waves (1-wave blocks) per batch

typedef _Float16 half8 __attribute__((ext_vector_type(8)));
typedef _Float16 half4v __attribute__((ext_vector_type(4)));
typedef float f32x4 __attribute__((ext_vector_type(4)));

// ---- bool-input dtype shim: harness may pass jnp.bool as int32 or uint8 ----
__device__ __forceinline__ bool bools_are_i32(const void* mask) {
  return ((const unsigned int*)mask)[0] == 1u;
}
__device__ __forceinline__ int bget(const void* p, int idx, bool i32) {
  return i32 ? ((const int*)p)[idx] : (int)((const unsigned char*)p)[idx];
}

// ---- DPP wave-64 reductions (VALU only) ----
__device__ __forceinline__ float wave_sum_f32(float x) {
  int t;
#define STEP(ctrl)                                                         \
  t = __builtin_amdgcn_update_dpp(0, __float_as_int(x), ctrl, 0xf, 0xf,    \
                                  true);                                   \
  x += __int_as_float(t);
  STEP(0x111) STEP(0x112) STEP(0x114) STEP(0x118) STEP(0x142) STEP(0x143)
#undef STEP
  return __int_as_float(__builtin_amdgcn_readlane(__float_as_int(x), 63));
}

__device__ __forceinline__ int wave_sum_i32(int x) {
  int t;
#define STEP(ctrl)                                                      \
  t = __builtin_amdgcn_update_dpp(0, x, ctrl, 0xf, 0xf, true);          \
  x += t;
  STEP(0x111) STEP(0x112) STEP(0x114) STEP(0x118) STEP(0x142) STEP(0x143)
#undef STEP
  return __builtin_amdgcn_readlane(x, 63);
}

__device__ __forceinline__ int bytesum4(unsigned int u) {
  return (int)((u * 0x01010101u) >> 24);  // bytes are 0/1, sum <= 4
}

// ---------------- z1: 16 chains/wave via MFMA ------------------------------
// Each wave advances 16 independent chunk-chains; the 16x(64x64) matvec batch
// is ONE 16x64 @ 64x64 product = 8x mfma_f32_16x16x32_f16 per iteration.
// Formulation D = ET^T @ P^T: chains on the N dim.
//   B-frag (P^T): col = chain = lane&15, k = prev-state, read from LDS
//     p[c][state] as contiguous 8 f16 (b128) at states 8*(lane>>4)+{0..7}
//     (+32 for the second K-half).
//   A-frag (ET^T): built analytically with the SAME k-indexing -> any k-
//     permutation error in the assumed fragment layout cancels in the dot.
//   D (m89-verified): col = lane&15 = chain, row = 4*(lane>>4)+reg = state
//     within tile -> lane holds 16 states of ITS chain: per-chain renorm =
//     in-lane max + shfl_xor(16) + shfl_xor(32).
// Per-step exact renorm (p normalized by max of matvec output, S += log M)
// == the R6-R13 verified scheme reparametrized; f16 p as verified.
__global__ __launch_bounds__(64, 1) void crf_z1(
    const float* __restrict__ em, const void* __restrict__ mask,
    const float* __restrict__ trans, const float* __restrict__ startv,
    const float* __restrict__ endv, const void* __restrict__ ftr,
    const void* __restrict__ fst, const void* __restrict__ fen,
    float* __restrict__ out) {
  const int lane = threadIdx.x;
  const int b = blockIdx.x >> 3;   // WPB == 8
  const int w = blockIdx.x & 7;
  const bool i32 = bools_are_i32(mask);

  // len[b] = sum(mask[b, :])
  int ls = 0;
  if (i32) {
    const uint4* mv = (const uint4*)((const int*)mask + (size_t)b * TT);
#pragma unroll
    for (int k = 0; k < 16; ++k) {               // 1024 uint4 = 4096 ints
      uint4 u = mv[k * 64 + lane];
      ls += (int)(u.x + u.y + u.z + u.w);
    }
  } else {
    const uint4* mv = (const uint4*)((const unsigned char*)mask + (size_t)b * TT);
#pragma unroll
    for (int k = 0; k < 4; ++k) {                // 256 uint4 = 4096 bytes
      uint4 u = mv[k * 64 + lane];
      ls += bytesum4(u.x) + bytesum4(u.y) + bytesum4(u.z) + bytesum4(u.w);
    }
  }
  const int len = wave_sum_i32(ls);

  const int c = lane & 15;          // this lane's chain (chunk 16w + c)
  const int g = lane >> 4;          // lane group
  const int L = (16 * w + c) * CHUNK;
  const bool act = (L < len);
  const bool isC0 = (w == 0) && (c == 0);   // true sequence start
  const int tlo = isC0 ? 1 : (L - WARM + 1);
  const int thi = min(L + CHUNK - 1, len - 1);
  const bool hasend = (len <= L + CHUNK);

  // A fragments: ET^T slab rows 16n..16n+15, K-half h.
  // element i of lane: ET[32h + 8g + i][16n + c] = exp(masked trans)
  half8 etf[4][2];
#pragma unroll
  for (int n = 0; n < 4; ++n)
#pragma unroll
    for (int h = 0; h < 2; ++h) {
      half8 f;
#pragma unroll
      for (int i = 0; i < 8; ++i) {
        int k = 32 * h + 8 * g + i;
        int j = 16 * n + c;
        float tv = trans[k * NN + j];
        if (bget(ftr, k * NN + j, i32)) tv = IMPOSSIBLE;
        f[i] = (_Float16)__expf(tv);
      }
      etf[n][h] = f;
    }

  // end factors in D domain: element e = 4n+r -> state j = 16n + 4g + r
  float eefin[16];
#pragma unroll
  for (int n = 0; n < 4; ++n)
#pragma unroll
    for (int r = 0; r < 4; ++r) {
      int j = 16 * n + 4 * g + r;
      float evv = endv[j];
      if (bget(fen, j, i32)) evv = IMPOSSIBLE;
      eefin[4 * n + r] = hasend ? __expf(evv) : 1.0f;
    }

  // p[chain][state] f16, row stride 72 elems (144B) to spread LDS banks
  __shared__ __align__(16) _Float16 pls[16 * 72];

  const float* emB = em + (size_t)b * TT * NN;

  // init p rows at t0r (warm start) / exact start for chunk 0
  const int t0r = isC0 ? 0 : (L - WARM);
#pragma unroll
  for (int rr = 0; rr < 2; ++rr) {
    const int j0 = 8 * g + 32 * rr;
    float ev[8];
    *(float4*)&ev[0] = *(const float4*)(emB + t0r * NN + j0);
    *(float4*)&ev[4] = *(const float4*)(emB + t0r * NN + j0 + 4);
    if (isC0) {
#pragma unroll
      for (int i = 0; i < 8; ++i) {
        float sv = startv[j0 + i];
        if (bget(fst, j0 + i, i32)) sv = IMPOSSIBLE;
        ev[i] += sv;
      }
    }
    half8 hv;
#pragma unroll
    for (int i = 0; i < 8; ++i) hv[i] = (_Float16)__expf(ev[i]);
    *(half8*)&pls[c * 72 + j0] = hv;
  }

  float S = 0.f, zres = 0.f;

  // em ring depth 2, two NAMED slots (no runtime-indexed arrays -> no scratch)
  float4 emrA[4], emrB[4];
#pragma unroll
  for (int n = 0; n < 4; ++n) {
    int tA = min(tlo + 0, TT - 1);
    int tB = min(tlo + 1, TT - 1);
    emrA[n] = *(const float4*)(emB + tA * NN + 16 * n + 4 * g);
    emrB[n] = *(const float4*)(emB + tB * NN + 16 * n + 4 * g);
  }

  const int cg = (len - 1) / CHUNK;  // chunk holding the last step
  const int ie = ((cg >> 4) == w) ? (len - 1 - (cg * CHUNK - WARM + 1)) : -1;

  auto step = [&](int i, float4* emr) {
    // current E = exp(em[t_c]) (loaded 2 iters ago: off the critical chain)
    float eex[16];
#pragma unroll
    for (int n = 0; n < 4; ++n) {
      eex[4 * n + 0] = __expf(emr[n].x);
      eex[4 * n + 1] = __expf(emr[n].y);
      eex[4 * n + 2] = __expf(emr[n].z);
      eex[4 * n + 3] = __expf(emr[n].w);
    }
    // prefetch t for iteration i+2 into this slot
    {
      int t2 = min(tlo + i + 2, TT - 1);
#pragma unroll
      for (int n = 0; n < 4; ++n)
        emr[n] = *(const float4*)(emB + t2 * NN + 16 * n + 4 * g);
    }
    // B fragments: previous p, contiguous 8 states per K-half
    half8 bf0 = *(const half8*)&pls[c * 72 + 8 * g];
    half8 bf1 = *(const half8*)&pls[c * 72 + 32 + 8 * g];
    // 8 MFMAs: 4 output tiles x 2 K-halves (accumulate)
    f32x4 a0 = {0.f, 0.f, 0.f, 0.f}, a1 = a0, a2 = a0, a3 = a0;
    a0 = __builtin_amdgcn_mfma_f32_16x16x32_f16(etf[0][0], bf0, a0, 0, 0, 0);
    a1 = __builtin_amdgcn_mfma_f32_16x16x32_f16(etf[1][0], bf0, a1, 0, 0, 0);
    a2 = __builtin_amdgcn_mfma_f32_16x16x32_f16(etf[2][0], bf0, a2, 0, 0, 0);
    a3 = __builtin_amdgcn_mfma_f32_16x16x32_f16(etf[3][0], bf0, a3, 0, 0, 0);
    a0 = __builtin_amdgcn_mfma_f32_16x16x32_f16(etf[0][1], bf1, a0, 0, 0, 0);
    a1 = __builtin_amdgcn_mfma_f32_16x16x32_f16(etf[1][1], bf1, a1, 0, 0, 0);
    a2 = __builtin_amdgcn_mfma_f32_16x16x32_f16(etf[2][1], bf1, a2, 0, 0, 0);
    a3 = __builtin_amdgcn_mfma_f32_16x16x32_f16(etf[3][1], bf1, a3, 0, 0, 0);
    // per-chain max of the matvec output (pre-em)
    float M = fmaxf(fmaxf(fmaxf(a0[0], a0[1]), fmaxf(a0[2], a0[3])),
                    fmaxf(fmaxf(fmaxf(a1[0], a1[1]), fmaxf(a1[2], a1[3])),
                          fmaxf(fmaxf(fmaxf(a2[0], a2[1]), fmaxf(a2[2], a2[3])),
                                fmaxf(fmaxf(a3[0], a3[1]),
                                      fmaxf(a3[2], a3[3])))));
    M = fmaxf(M, __shfl_xor(M, 16, 64));
    M = fmaxf(M, __shfl_xor(M, 32, 64));
    const float rM = 1.0f / M;
    // p_new = (s / M) * exp(em);  bounded by exp(max em) ~ 245: f16-safe
    float pn[16];
#pragma unroll
    for (int r = 0; r < 4; ++r) pn[0 + r]  = a0[r] * rM * eex[0 + r];
#pragma unroll
    for (int r = 0; r < 4; ++r) pn[4 + r]  = a1[r] * rM * eex[4 + r];
#pragma unroll
    for (int r = 0; r < 4; ++r) pn[8 + r]  = a2[r] * rM * eex[8 + r];
#pragma unroll
    for (int r = 0; r < 4; ++r) pn[12 + r] = a3[r] * rM * eex[12 + r];
    // writeback f16: tile n -> states 16n + 4g + {0..3} of chain c (b64)
#pragma unroll
    for (int n = 0; n < 4; ++n) {
      half4v hq;
      hq[0] = (_Float16)pn[4 * n + 0];
      hq[1] = (_Float16)pn[4 * n + 1];
      hq[2] = (_Float16)pn[4 * n + 2];
      hq[3] = (_Float16)pn[4 * n + 3];
      *(half4v*)&pls[c * 72 + 16 * n + 4 * g] = hq;
    }
    S += __logf(M);
    // gated special iterations (wave-uniform conditions)
    if (i == WARM - 2 || i == NI - 1 || i == ie || ((w == 0) && (i == 30))) {
      if (i == WARM - 2) {
        // warm-up discard at t = L-1: S := -log(sum_j p)
        float ps = 0.f;
#pragma unroll
        for (int e = 0; e < 16; ++e) ps += pn[e];
        ps += __shfl_xor(ps, 16, 64);
        ps += __shfl_xor(ps, 32, 64);
        if (!isC0) S = -__logf(ps);
      } else {
        // chunk-final capture: zc = S + log(sum_j p * (hasend ? ee : 1))
        float vs = 0.f;
#pragma unroll
        for (int e = 0; e < 16; ++e) vs = fmaf(pn[e], eefin[e], vs);
        vs += __shfl_xor(vs, 16, 64);
        vs += __shfl_xor(vs, 32, 64);
        const bool fin = act && (tlo + i == thi);
        float zc = S + __logf(vs);
        zres = fin ? zc : zres;
      }
    }
  };

  for (int i = 0; i < NI; i += 2) {
    step(i, emrA);
    if (i + 1 < NI) step(i + 1, emrB);
  }

  const float tot = wave_sum_f32((lane < 16) ? zres : 0.f);
  if (lane == 0) atomicAdd(out + b, tot);
}

// ---------------- z0: gold-path score, wave-per-row ballot version ----------
// (unchanged: ~12 us under the overhead model)
__global__ __launch_bounds__(256) void crf_z0(
    const float* __restrict__ em, const void* __restrict__ mask,
    const void* __restrict__ target, const float* __restrict__ trans,
    const float* __restrict__ startv, const float* __restrict__ endv,
    const void* __restrict__ ftr, const void* __restrict__ fst,
    const void* __restrict__ fen, float* __restrict__ out) {
  const int tid = threadIdx.x;
  const int lane = tid & 63;
  const int w = tid >> 6;
  const int b = blockIdx.x >> 4;
  const int q = blockIdx.x & 15;
  const bool i32 = bools_are_i32(mask);

  __shared__ int lred[4];
  __shared__ int tags[257];
  __shared__ float fred4[4];

  // ---- block-wide len[b] = sum(mask[b,:]) ----
  int ls = 0;
  if (i32) {
    const uint4* mv = (const uint4*)((const int*)mask + (size_t)b * TT);
#pragma unroll
    for (int k = 0; k < 4; ++k) {   // 1024 uint4 = 4096 ints
      uint4 u = mv[k * 256 + tid];
      ls += (int)(u.x + u.y + u.z + u.w);
    }
  } else {
    uint4 u = ((const uint4*)((const unsigned char*)mask + (size_t)b * TT))[tid];
    ls = bytesum4(u.x) + bytesum4(u.y) + bytesum4(u.z) + bytesum4(u.w);
  }
  ls = wave_sum_i32(ls);
  if (lane == 0) lred[w] = ls;

  // ---- tag extraction: wave w scans rows t0 + w*64 .. +63 ----
  const int t0 = q * 256;
  int mytag = 0;
  const size_t rb = ((size_t)b * TT + t0 + (size_t)w * 64) * NN + lane;
  if (i32) {
    const int* tg = (const int*)target + rb;
    for (int k = 0; k < 8; ++k) {
      int v[8];
#pragma unroll
      for (int j = 0; j < 8; ++j) v[j] = tg[(size_t)(k * 8 + j) * NN];
#pragma unroll
      for (int j = 0; j < 8; ++j) {
        unsigned long long bm = __ballot(v[j] != 0);
        int tv = __ffsll(bm) - 1;
        if (lane == k * 8 + j) mytag = tv;
      }
    }
  } else {
    const unsigned char* tg = (const unsigned char*)target + rb;
    for (int k = 0; k < 8; ++k) {
      int v[8];
#pragma unroll
      for (int j = 0; j < 8; ++j) v[j] = (int)tg[(size_t)(k * 8 + j) * NN];
#pragma unroll
      for (int j = 0; j < 8; ++j) {
        unsigned long long bm = __ballot(v[j] != 0);
        int tv = __ffsll(bm) - 1;
        if (lane == k * 8 + j) mytag = tv;
      }
    }
  }
  tags[tid + 1] = mytag;
  if (w == 0) {  // boundary row t0-1 for the block's first transition
    int rp = (t0 == 0) ? 0 : t0 - 1;
    int vv = i32 ? ((const int*)target)[((size_t)b * TT + rp) * NN + lane]
                 : (int)((const unsigned char*)
                       target)[((size_t)b * TT + rp) * NN + lane];
    unsigned long long bm = __ballot(vv != 0);
    int tv = __ffsll(bm) - 1;
    if (tid == 0) tags[0] = (t0 == 0) ? 0 : tv;
  }
  __syncthreads();  // publish lred + tags
  const int len = lred[0] + lred[1] + lred[2] + lred[3];

  const int t = t0 + tid;
  float contrib = 0.f;
  if (t < len) {
    int tg = tags[tid + 1];
    float emv = em[((size_t)b * TT + t) * NN + tg];
    if (t == 0) {
      float sv = startv[tg];
      if (bget(fst, tg, i32)) sv = IMPOSSIBLE;
      contrib = sv + emv;
    } else {
      int tp = tags[tid];
      float tv = trans[tp * NN + tg];
      if (bget(ftr, tp * NN + tg, i32)) tv = IMPOSSIBLE;
      contrib = tv + emv;
    }
    if (t == len - 1) {
      float evv = endv[tg];
      if (bget(fen, tg, i32)) evv = IMPOSSIBLE;
      contrib += evv;
    }
  }
  float wsum = wave_sum_f32(contrib);
  if (lane == 0) fred4[w] = wsum;
  __syncthreads();
  if (tid == 0)
    atomicAdd(out + b, -(fred4[0] + fred4[1] + fred4[2] + fred4[3]));
}

extern "C" void kernel_launch(void* const* d_in, const int* in_sizes, int n_in,
                              void* d_out, int out_size, void* d_ws,
                              size_t ws_size, hipStream_t stream) {
  const float* em = (const float*)d_in[0];
  const void* mask = d_in[1];
  const void* target = d_in[2];
  const float* trans = (const float*)d_in[3];
  const float* startv = (const float*)d_in[4];
  const float* endv = (const float*)d_in[5];
  const void* ftr = d_in[6];
  const void* fst = d_in[7];
  const void* fen = d_in[8];
  float* out = (float*)d_out;

  hipMemsetAsync(out, 0, BB * sizeof(float), stream);
  crf_z1<<<dim3(BB * WPB), dim3(64), 0, stream>>>(em, mask, trans, startv,
                                                  endv, ftr, fst, fen, out);
  crf_z0<<<dim3(BB * 16), dim3(256), 0, stream>>>(
      em, mask, target, trans, startv, endv, ftr, fst, fen, out);
}